// Round 16
// baseline (520.100 us; speedup 1.0000x reference)
//
#include <hip/hip_runtime.h>
#include <hip/hip_bf16.h>

// ============================================================================
// VQ-VAE forward, round 16: R15 + NSUB (N-split) for encoder convs.
//  conv1/2/3 were 512 blocks = 2/CU (occupancy 17.5%, MfmaUtil 40%).
//  conv_ad gains NSUB (16-col subtiles per block): NSUB=2 -> BN=32,
//  grid.y doubles -> 1024 blocks = 4/CU; B-LDS 32->16KB; acc VGPR halves.
//  conv0 keeps NSUB=4. Everything else identical to R15.
// ============================================================================

#define TPB 256
typedef __attribute__((ext_vector_type(8))) short short8v;
typedef __attribute__((ext_vector_type(4))) float f32x4;
typedef unsigned int u32;
typedef unsigned short u16;

__device__ inline u16 f2bf(float x){
  union { __hip_bfloat16 b; u16 u; } cv;
  cv.b = __float2bfloat16(x);
  return cv.u;
}
__device__ inline float bf2f(u16 h){ union{u32 u;float f;}v; v.u=((u32)h)<<16; return v.f;}

template<int NS>
__device__ inline void splitN(float x, u16 t[3]) {
  u16 h0 = f2bf(x); t[0] = h0;
  float r1 = x - bf2f(h0);
  u16 h1 = f2bf(r1); t[1] = h1;
  if (NS == 3) { float r2 = r1 - bf2f(h1); t[2] = f2bf(r2); }
}

template<int NS, int ST>
__device__ inline void stW(u32* L, int row, int oct, const u16 hs[3][8]) {
  constexpr int SWM = (ST == 64) ? 15 : 7;
  const int sw = row & SWM;
#pragma unroll
  for (int s = 0; s < NS; ++s) {
    uint4 d;
    d.x = (u32)hs[s][0] | ((u32)hs[s][1] << 16);
    d.y = (u32)hs[s][2] | ((u32)hs[s][3] << 16);
    d.z = (u32)hs[s][4] | ((u32)hs[s][5] << 16);
    d.w = (u32)hs[s][6] | ((u32)hs[s][7] << 16);
    int ch = (((s << 2) | oct) ^ sw) << 2;
    *reinterpret_cast<uint4*>(&L[row * ST + ch]) = d;
  }
}

template<int NS, int ST>
__device__ inline void stWf(u32* L, int row, int oct, const float v[8]) {
  u16 hs[3][8];
#pragma unroll
  for (int e = 0; e < 8; ++e) {
    u16 t3[3]; splitN<(NS == 3) ? 3 : 2>(v[e], t3);
    hs[0][e] = t3[0]; hs[1][e] = t3[1]; if (NS == 3) hs[2][e] = t3[2];
  }
  stW<NS, ST>(L, row, oct, hs);
}

template<int ST>
__device__ inline void stWp(u32* L, int row, int oct, int s, uint4 d) {
  constexpr int SWM = (ST == 64) ? 15 : 7;
  int ch = (((s << 2) | oct) ^ (row & SWM)) << 2;
  *reinterpret_cast<uint4*>(&L[row * ST + ch]) = d;
}

template<int ST>
__device__ inline short8v rdFrag(const u32* L, int row, int c) {
  constexpr int SWM = (ST == 64) ? 15 : 7;
  int ph = (c ^ (row & SWM)) << 2;
  return *reinterpret_cast<const short8v*>(&L[row * ST + ph]);
}

// ---------------- weight preps (split for lifetime safety) -------------------
__device__ inline u16 wprep1_elem(const float* __restrict__ src, int i,
                                  int Ci, int Co) {
  int K4 = Ci << 2;
  int par = i / (Co * K4); int rem = i - par * (Co * K4);
  int co = rem / K4; int k4 = rem - co * K4;
  int ci = k4 >> 2, ay = (k4 >> 1) & 1, ax = k4 & 1;
  int py = par >> 1, px = par & 1;
  int widx = ((1 - py) << 2) + (1 - px) + (ay << 3) + (ax << 1);
  return f2bf(src[(((size_t)ci * Co + co) << 4) + widx]);
}
__device__ inline void wsplit3_elem(const float* __restrict__ src,
                                    u16* __restrict__ dst, int i, int n) {
  u16 t3[3]; splitN<3>(src[i], t3);
  dst[i] = t3[0]; dst[i + n] = t3[1]; dst[i + 2 * n] = t3[2];
}

__global__ __launch_bounds__(TPB) void prep_enc_k(
    const float* __restrict__ ew0, const float* __restrict__ ew1,
    const float* __restrict__ ew2, const float* __restrict__ ew3,
    u16* __restrict__ WE0, u16* __restrict__ WE1,
    u16* __restrict__ WE2, u16* __restrict__ WE3)
{
  int idx = blockIdx.x * TPB + threadIdx.x;
  if (idx < 3072)     { wsplit3_elem(ew0, WE0, idx, 3072); return; }
  if (idx < 68608)    { wsplit3_elem(ew1, WE1, idx - 3072, 65536); return; }
  if (idx < 199680)   { wsplit3_elem(ew2, WE2, idx - 68608, 131072); return; }
  if (idx < 723968)   { wsplit3_elem(ew3, WE3, idx - 199680, 524288); return; }
}

__global__ __launch_bounds__(TPB) void prep_dec_k(
    const float* __restrict__ tw0, const float* __restrict__ tw1,
    const float* __restrict__ tw2,
    u16* __restrict__ WT0, u16* __restrict__ WT1, u16* __restrict__ WT2)
{
  int idx = blockIdx.x * TPB + threadIdx.x;
  if (idx < 524288)   { WT0[idx] = wprep1_elem(tw0, idx, 256, 128); return; }
  if (idx < 655360)   { WT1[idx - 524288] = wprep1_elem(tw1, idx - 524288, 128, 64); return; }
  if (idx < 720896)   { WT2[idx - 655360] = wprep1_elem(tw2, idx - 655360, 64, 64); return; }
}

// ---------------- fused input pad / border-zero ------------------------------
__global__ __launch_bounds__(TPB) void prep_inp_k(
    const float* __restrict__ x, float* __restrict__ xp,
    float* __restrict__ h0p)
{
  int idx = blockIdx.x * TPB + threadIdx.x;
  if (idx < 3345408) {
    int px = idx % 66; int t = idx / 66; int py = t % 66; int p = t / 66;
    float v = 0.f;
    if (py >= 1 && py <= 64 && px >= 1 && px <= 64)
      v = x[(size_t)p * 4096 + (py - 1) * 64 + (px - 1)];
    xp[idx] = v;
  } else if (idx < 5508096) {
    int i2 = idx - 3345408;
    int p = i2 / 132, k = i2 % 132;
    int py, px;
    if (k < 34)       { py = 0;           px = k; }
    else if (k < 68)  { py = 33;          px = k - 34; }
    else if (k < 100) { py = k - 68 + 1;  px = 0; }
    else              { py = k - 100 + 1; px = 33; }
    h0p[(size_t)p * 1156 + py * 34 + px] = 0.f;
  }
}

// ---------------- A-direct MFMA conv (s2,k4,p1), NS=3, NSUB n-split ---------
// NSUB = number of 16-col output subtiles per block (4 -> BN=64, 2 -> BN=32).
template<int RM, int OUTM, int NSUB>
__global__ __launch_bounds__(TPB, 2) void conv_ad(
    const float* __restrict__ in, const u16* __restrict__ wsp,
    const float* __restrict__ bias, float* __restrict__ outp,
    int Ci, int Co, int Wi, int lwo, int relu, int KSPL, int PS,
    int bS, int ciS, int Mtot)
{
  constexpr int BM = RM * 64;
  constexpr int NB = NSUB * 16;          // B rows in LDS
  constexpr int BACT = NB * 4;           // active staging threads
  __shared__ __align__(16) u32 BL[2][NB * 64];
  const int K = Ci << 4;
  const int PW = Wi + 2;
  const int Wo = Wi >> 1;
  const int tid = threadIdx.x;
  const int m0 = blockIdx.x * BM, n0 = blockIdx.y * NB;
  const int lane = tid & 63, wv = tid >> 6, r = lane & 15, g = lane >> 4;
  const int kb0 = blockIdx.z * KSPL;
  const int kbN = min(kb0 + KSPL, K);
  const int khsel = g & 1;
  const int cig = g >> 1;
  f32x4 acc[RM][NSUB] = {};

  int base[RM];
#pragma unroll
  for (int mm = 0; mm < RM; ++mm) {
    int cell = m0 + (wv * RM + mm) * 16 + r;
    int x = cell & (Wo - 1), y = (cell >> lwo) & (Wo - 1), b = cell >> (lwo + lwo);
    base[mm] = b * bS + (2 * y + 2 * khsel) * PW + 2 * x;
  }

  auto gA = [&](int kb, float v[RM][8]) {
    if ((kb + (g << 3)) < K) {
      int cioff = ((kb >> 4) + cig) * ciS;
#pragma unroll
      for (int mm = 0; mm < RM; ++mm) {
        const float* p = in + base[mm] + cioff;
#pragma unroll
        for (int e = 0; e < 8; ++e)
          v[mm][e] = p[(e >> 2) * PW + (e & 3)];
      }
    } else {
#pragma unroll
      for (int mm = 0; mm < RM; ++mm)
#pragma unroll
        for (int e = 0; e < 8; ++e) v[mm][e] = 0.f;
    }
  };
  auto gB = [&](int kb, uint4* d) {
    if (tid < BACT) {
      int n = tid & (NB - 1), oc2 = tid / NB;
      int k8 = kb + (oc2 << 3);
      if (k8 < K) {
        const u16* wp = wsp + (size_t)(n0 + n) * K + k8;
        d[0] = *reinterpret_cast<const uint4*>(wp);
        d[1] = *reinterpret_cast<const uint4*>(wp + PS);
        d[2] = *reinterpret_cast<const uint4*>(wp + 2 * PS);
        return;
      }
    }
    d[0] = d[1] = d[2] = make_uint4(0u, 0u, 0u, 0u);
  };
  auto mkfrags = [&](const float v[8], short8v f[3]) {
    u16 hs[3][8];
#pragma unroll
    for (int e = 0; e < 8; ++e) {
      u16 t3[3]; splitN<3>(v[e], t3);
      hs[0][e] = t3[0]; hs[1][e] = t3[1]; hs[2][e] = t3[2];
    }
#pragma unroll
    for (int s = 0; s < 3; ++s) {
      union { u16 u[8]; short8v sv; } cv;
#pragma unroll
      for (int e = 0; e < 8; ++e) cv.u[e] = hs[s][e];
      f[s] = cv.sv;
    }
  };

  float vA[RM][8], vA2[RM][8];
  uint4 vB[3], vB2[3];
  gA(kb0, vA); gB(kb0, vB);
  for (int kb = kb0; kb < kbN; kb += 32) {
    u32* BLc = BL[((kb - kb0) >> 5) & 1];
    if (tid < BACT) {
      int n = tid & (NB - 1), oc2 = tid / NB;
      stWp<64>(BLc, n, oc2, 0, vB[0]);
      stWp<64>(BLc, n, oc2, 1, vB[1]);
      stWp<64>(BLc, n, oc2, 2, vB[2]);
    }
    const bool more = (kb + 32) < kbN;
    if (more) { gB(kb + 32, vB2); gA(kb + 32, vA2); }
    short8v a_[RM][3];
#pragma unroll
    for (int mm = 0; mm < RM; ++mm) mkfrags(vA[mm], a_[mm]);
    __syncthreads();
#pragma unroll
    for (int ns = 0; ns < NSUB; ++ns) {
      short8v b_[3];
#pragma unroll
      for (int s = 0; s < 3; ++s) b_[s] = rdFrag<64>(BLc, (ns << 4) + r, (s << 2) | g);
#pragma unroll
      for (int mm = 0; mm < RM; ++mm) {
        acc[mm][ns] = __builtin_amdgcn_mfma_f32_16x16x32_bf16(a_[mm][0], b_[0], acc[mm][ns], 0, 0, 0);
        acc[mm][ns] = __builtin_amdgcn_mfma_f32_16x16x32_bf16(a_[mm][0], b_[1], acc[mm][ns], 0, 0, 0);
        acc[mm][ns] = __builtin_amdgcn_mfma_f32_16x16x32_bf16(a_[mm][1], b_[0], acc[mm][ns], 0, 0, 0);
        acc[mm][ns] = __builtin_amdgcn_mfma_f32_16x16x32_bf16(a_[mm][1], b_[1], acc[mm][ns], 0, 0, 0);
        acc[mm][ns] = __builtin_amdgcn_mfma_f32_16x16x32_bf16(a_[mm][0], b_[2], acc[mm][ns], 0, 0, 0);
        acc[mm][ns] = __builtin_amdgcn_mfma_f32_16x16x32_bf16(a_[mm][2], b_[0], acc[mm][ns], 0, 0, 0);
      }
    }
    if (more) {
#pragma unroll
      for (int mm = 0; mm < RM; ++mm)
#pragma unroll
        for (int e = 0; e < 8; ++e) vA[mm][e] = vA2[mm][e];
#pragma unroll
      for (int s = 0; s < 3; ++s) vB[s] = vB2[s];
    }
  }
#pragma unroll
  for (int mm = 0; mm < RM; ++mm)
#pragma unroll
    for (int ns = 0; ns < NSUB; ++ns) {
      int c0 = m0 + (wv * RM + mm) * 16 + (g << 2);
      int co = n0 + (ns << 4) + r;
      if (OUTM == 0) {
        float bv = bias[co];
        const int OPW = Wo + 2;
        const int OPHW = OPW * OPW;
#pragma unroll
        for (int q = 0; q < 4; ++q) {
          int cell = c0 + q;
          int x = cell & (Wo - 1), y = (cell >> lwo) & (Wo - 1), b = cell >> (lwo + lwo);
          float v = acc[mm][ns][q] + bv;
          if (relu) v = fmaxf(v, 0.f);
          outp[((size_t)(b * Co + co)) * OPHW + (y + 1) * OPW + (x + 1)] = v;
        }
      } else {
        float4 o;
        o.x = acc[mm][ns][0]; o.y = acc[mm][ns][1];
        o.z = acc[mm][ns][2]; o.w = acc[mm][ns][3];
        *reinterpret_cast<float4*>(
            &outp[((size_t)(blockIdx.z * Co + co)) * Mtot + c0]) = o;
      }
    }
}

// ---------------- conv combines ----------------------------------------------
__global__ __launch_bounds__(TPB) void combine_cm_k(
    const float* __restrict__ P, const float* __restrict__ bias,
    float* __restrict__ out)
{
  int idx = blockIdx.x * TPB + threadIdx.x;
  if (idx >= 5308416) return;
  int px = idx % 18; int t = idx / 18; int py = t % 18; t /= 18;
  int b = t % 256; int co = t / 256;
  float v = 0.f;
  if (py >= 1 && py <= 16 && px >= 1 && px <= 16) {
    int cell = b * 256 + (py - 1) * 16 + (px - 1);
    v = P[(size_t)co * 65536 + cell] + P[(size_t)(64 + co) * 65536 + cell] + bias[co];
    v = fmaxf(v, 0.f);
  }
  out[idx] = v;
}

__global__ __launch_bounds__(TPB) void combine_pad_k(
    const float* __restrict__ P, const float* __restrict__ bias,
    float* __restrict__ out)
{
  int idx = blockIdx.x * TPB + threadIdx.x;
  if (idx >= 3276800) return;
  int px = idx % 10; int t = idx / 10; int py = t % 10; t /= 10;
  int co = t % 128; int b = t / 128;
  float v = 0.f;
  if (py >= 1 && py <= 8 && px >= 1 && px <= 8) {
    int cell = b * 64 + (py - 1) * 8 + (px - 1);
    float s = 0.f;
#pragma unroll
    for (int z = 0; z < 4; ++z)
      s += P[((size_t)(z * 128 + co)) * 16384 + cell];
    v = fmaxf(s + bias[co], 0.f);
  }
  out[idx] = v;
}

__global__ __launch_bounds__(TPB) void conv_combine(
    const float* __restrict__ P, const float* __restrict__ bias,
    float* __restrict__ out, int Mtot, int N, int SK, int lwo, int relu)
{
  int idx = blockIdx.x * TPB + threadIdx.x;
  int mq = Mtot >> 2;
  int co = idx / mq;
  int cell0 = (idx - co * mq) << 2;
  if (co >= N) return;
  float4 s = make_float4(0.f, 0.f, 0.f, 0.f);
  for (int z = 0; z < SK; ++z) {
    const float4 pv = *reinterpret_cast<const float4*>(
        &P[((size_t)z * N + co) * Mtot + cell0]);
    s.x += pv.x; s.y += pv.y; s.z += pv.z; s.w += pv.w;
  }
  float bv = bias[co];
  s.x += bv; s.y += bv; s.z += bv; s.w += bv;
  if (relu) { s.x = fmaxf(s.x, 0.f); s.y = fmaxf(s.y, 0.f);
              s.z = fmaxf(s.z, 0.f); s.w = fmaxf(s.w, 0.f); }
  int Wo = 1 << lwo;
  int x = cell0 & (Wo - 1), y = (cell0 >> lwo) & (Wo - 1), b = cell0 >> (lwo + lwo);
  *reinterpret_cast<float4*>(&out[(((size_t)b * N + co) * Wo + y) * Wo + x]) = s;
}

// ---------------- MFMA GEMM (BM=64, BN=64, 4 waves, split-K, prefetched) ----
template<int NS, int OUTM>
__global__ __launch_bounds__(TPB) void gemm_mf(
    const float* __restrict__ A, const float* __restrict__ W,
    const float* __restrict__ bias, void* __restrict__ outp,
    int M, int K, int N, int KSPL)
{
  constexpr int ST = (NS == 3) ? 64 : 32;
  __shared__ __align__(16) u32 L[(64 + 64) * ST];
  u32* AL = L; u32* BL = L + 64 * ST;
  const int tid = threadIdx.x;
  const int m0 = blockIdx.x << 6, n0 = blockIdx.y << 6;
  const int lane = tid & 63, wv = tid >> 6, r = lane & 15, g = lane >> 4;
  const int kb0 = blockIdx.z * KSPL;
  const int kbN = kb0 + KSPL;
  const int cl = tid & 63, oct = tid >> 6;
  f32x4 acc[4] = {};

  float vA[8], vB[8], vA2[8], vB2[8];
  auto gA = [&](int kt, float* v) {
    const float* ap = &A[(size_t)(m0 + cl) * K + kt + (oct << 3)];
    *reinterpret_cast<float4*>(&v[0]) = *reinterpret_cast<const float4*>(ap);
    *reinterpret_cast<float4*>(&v[4]) = *reinterpret_cast<const float4*>(ap + 4);
  };
  auto gB = [&](int kt, float* v) {
#pragma unroll
    for (int e = 0; e < 8; ++e)
      v[e] = W[(size_t)(kt + (oct << 3) + e) * N + n0 + cl];
  };

  gA(kb0, vA); gB(kb0, vB);
  for (int kt = kb0; kt < kbN; kt += 32) {
    const bool more = (kt + 32) < kbN;
    if (more) { gA(kt + 32, vA2); gB(kt + 32, vB2); }
    stWf<NS, ST>(AL, cl, oct, vA);
    stWf<NS, ST>(BL, cl, oct, vB);
    __syncthreads();
    short8v a_[3];
#pragma unroll
    for (int s = 0; s < NS; ++s) a_[s] = rdFrag<ST>(AL, (wv << 4) + r, (s << 2) | g);
#pragma unroll
    for (int ns = 0; ns < 4; ++ns) {
      short8v b_[3];
#pragma unroll
      for (int s = 0; s < NS; ++s) b_[s] = rdFrag<ST>(BL, (ns << 4) + r, (s << 2) | g);
      acc[ns] = __builtin_amdgcn_mfma_f32_16x16x32_bf16(a_[0], b_[0], acc[ns], 0, 0, 0);
      if (NS >= 2) {
        acc[ns] = __builtin_amdgcn_mfma_f32_16x16x32_bf16(a_[0], b_[1], acc[ns], 0, 0, 0);
        acc[ns] = __builtin_amdgcn_mfma_f32_16x16x32_bf16(a_[1], b_[0], acc[ns], 0, 0, 0);
      }
      if (NS == 3) {
        acc[ns] = __builtin_amdgcn_mfma_f32_16x16x32_bf16(a_[1], b_[1], acc[ns], 0, 0, 0);
        acc[ns] = __builtin_amdgcn_mfma_f32_16x16x32_bf16(a_[0], b_[2], acc[ns], 0, 0, 0);
        acc[ns] = __builtin_amdgcn_mfma_f32_16x16x32_bf16(a_[2], b_[0], acc[ns], 0, 0, 0);
      }
    }
    __syncthreads();
    if (more) {
#pragma unroll
      for (int e = 0; e < 8; ++e) { vA[e] = vA2[e]; vB[e] = vB2[e]; }
    }
  }
#pragma unroll
  for (int ns = 0; ns < 4; ++ns)
#pragma unroll
    for (int q = 0; q < 4; ++q) {
      int m = m0 + (wv << 4) + (g << 2) + q;
      int n = n0 + (ns << 4) + r;
      float v = acc[ns][q];
      if (OUTM == 0) ((float*)outp)[((size_t)blockIdx.z * M + m) * N + n] = v;
      else           ((u32*)outp)[(size_t)m * N + n] = (u32)f2bf(v + bias[n]);
    }
}

// ---------------- fc split-K combine ----------------------------------------
__global__ __launch_bounds__(TPB) void combine_k(
    const float* __restrict__ P, const float* __restrict__ bias,
    float* __restrict__ out, int MN, int N, int SK, int relu)
{
  int i4 = (blockIdx.x * TPB + threadIdx.x) << 2;
  if (i4 >= MN) return;
  float4 s = make_float4(0.f, 0.f, 0.f, 0.f);
  for (int z = 0; z < SK; ++z) {
    const float4 pv = *reinterpret_cast<const float4*>(&P[(size_t)z * MN + i4]);
    s.x += pv.x; s.y += pv.y; s.z += pv.z; s.w += pv.w;
  }
  int n = i4 % N;
  s.x += bias[n]; s.y += bias[n + 1]; s.z += bias[n + 2]; s.w += bias[n + 3];
  if (relu) { s.x = fmaxf(s.x, 0.f); s.y = fmaxf(s.y, 0.f);
              s.z = fmaxf(s.z, 0.f); s.w = fmaxf(s.w, 0.f); }
  *reinterpret_cast<float4*>(&out[i4]) = s;
}

// ---------------- g2 combine: sum 2 partials -> single bf16 in u32 ----------
__global__ __launch_bounds__(TPB) void combine_pk_k(
    const float* __restrict__ P, const float* __restrict__ bias,
    u32* __restrict__ out)
{
  int i4 = (blockIdx.x * TPB + threadIdx.x) << 2;
  if (i4 >= 1048576) return;
  const float4 p0 = *reinterpret_cast<const float4*>(&P[i4]);
  const float4 p1 = *reinterpret_cast<const float4*>(&P[1048576 + i4]);
  int n = i4 % 4096;
  uint4 o;
  o.x = (u32)f2bf(p0.x + p1.x + bias[n]);
  o.y = (u32)f2bf(p0.y + p1.y + bias[n + 1]);
  o.z = (u32)f2bf(p0.z + p1.z + bias[n + 2]);
  o.w = (u32)f2bf(p0.w + p1.w + bias[n + 3]);
  *reinterpret_cast<uint4*>(&out[i4]) = o;
}

// ---------------- A-direct MFMA convT, single bf16 term ---------------------
template<int RM, int EMIT, int SPLITIN>
__global__ __launch_bounds__(TPB) void convt_ad(
    const u32* __restrict__ in, const u16* __restrict__ wth,
    const float* __restrict__ bias, u32* __restrict__ outq,
    int Ci, int Co, int Hi, int lwi, int relu)
{
  constexpr int BM = RM * 64;
  constexpr int STC = BM + 4;
  constexpr int LB = 2 * 64 * 32;
  constexpr int LSZ = (LB > 16 * STC) ? LB : 16 * STC;
  __shared__ __align__(16) u32 L[LSZ];
  const int Wi = Hi, K4 = Ci << 2;
  const int HW = Hi * Wi, HWq = HW >> 2, Wiq = Wi >> 1;
  const int par = blockIdx.z, py = par >> 1, px = par & 1;
  const int tid = threadIdx.x;
  const int m0 = blockIdx.x * BM, n0 = blockIdx.y << 6;
  const int lane = tid & 63, wv = tid >> 6, r = lane & 15, g = lane >> 4;
  const int stepCi = SPLITIN ? HWq : HW;
  f32x4 acc[RM][4] = {};

  int offT[RM][4]; u32 mskT[RM][4];
#pragma unroll
  for (int mm = 0; mm < RM; ++mm) {
    int cell = m0 + (wv * RM + mm) * 16 + r;
    int X = cell & (Wi - 1), Y = (cell >> lwi) & (Wi - 1), b = cell >> (lwi + lwi);
#pragma unroll
    for (int t = 0; t < 4; ++t) {
      int ay = t >> 1, ax = t & 1;
      int gy = Y + py - ay, gx = X + px - ax;
      bool ok = (gy >= 0 && gy < Hi && gx >= 0 && gx < Wi);
      int gyc = min(max(gy, 0), Hi - 1), gxc = min(max(gx, 0), Wi - 1);
      if (SPLITIN) {
        int q = ((gyc & 1) << 1) | (gxc & 1);
        offT[mm][t] = q * (256 * Ci * HWq) + b * Ci * HWq + (gyc >> 1) * Wiq + (gxc >> 1);
      } else {
        offT[mm][t] = b * Ci * HW + gyc * Wi + gxc;
      }
      mskT[mm][t] = ok ? 0xffffffffu : 0u;
    }
  }

  auto gA = [&](int kb, u32 v[RM][8]) {
    int cib = ((kb >> 2) + (g << 1)) * stepCi;
#pragma unroll
    for (int mm = 0; mm < RM; ++mm)
#pragma unroll
      for (int e = 0; e < 8; ++e) {
        int t = e & 3;
        v[mm][e] = in[offT[mm][t] + cib + ((e >> 2) ? stepCi : 0)] & mskT[mm][t];
      }
  };
  auto gB = [&](int kb, uint4* d) {
    int n = tid & 63, oc2 = tid >> 6;
    *d = *reinterpret_cast<const uint4*>(
        wth + (size_t)(par * Co + n0 + n) * K4 + kb + (oc2 << 3));
  };

  u32 vA[RM][8], vA2[RM][8];
  uint4 vB, vB2;
  gA(0, vA); gB(0, &vB);
  int cur = 0;
  for (int kb = 0; kb < K4; kb += 32) {
    u32* BLc = L + cur * (64 * 32);
    {
      int n = tid & 63, oc2 = tid >> 6;
      stWp<32>(BLc, n, oc2, 0, vB);
    }
    const bool more = (kb + 32) < K4;
    if (more) { gB(kb + 32, &vB2); gA(kb + 32, vA2); }
    short8v a_[RM];
#pragma unroll
    for (int mm = 0; mm < RM; ++mm) {
      const u32* v = vA[mm];
      union { uint4 u; short8v s; } ch;
      ch.u.x = (v[0] & 0xffffu) | (v[1] << 16);
      ch.u.y = (v[2] & 0xffffu) | (v[3] << 16);
      ch.u.z = (v[4] & 0xffffu) | (v[5] << 16);
      ch.u.w = (v[6] & 0xffffu) | (v[7] << 16);
      a_[mm] = ch.s;
    }
    __syncthreads();
#pragma unroll
    for (int ns = 0; ns < 4; ++ns) {
      short8v b0 = rdFrag<32>(BLc, (ns << 4) + r, g);
#pragma unroll
      for (int mm = 0; mm < RM; ++mm)
        acc[mm][ns] = __builtin_amdgcn_mfma_f32_16x16x32_bf16(a_[mm], b0, acc[mm][ns], 0, 0, 0);
    }
    if (more) {
#pragma unroll
      for (int mm = 0; mm < RM; ++mm)
#pragma unroll
        for (int e = 0; e < 8; ++e) vA[mm][e] = vA2[mm][e];
      vB = vB2;
    }
    cur ^= 1;
  }
  const size_t QO = (size_t)256 * Co * HW;
  constexpr int C4N = BM / 4;
#pragma unroll
  for (int ph = 0; ph < 4; ++ph) {
    __syncthreads();
    float bv = bias[n0 + (ph << 4) + r];
#pragma unroll
    for (int mm = 0; mm < RM; ++mm)
#pragma unroll
      for (int q = 0; q < 4; ++q) {
        int cell = (wv * RM + mm) * 16 + (g << 2) + q;
        float v = acc[mm][ph][q] + bv;
        if (relu) v = fmaxf(v, 0.f);
        L[r * STC + cell] = (u32)f2bf(v);
      }
    __syncthreads();
    if (EMIT == 2) {
      u16* op16 = (u16*)outq + (size_t)par * QO;
      constexpr int C8N = BM / 8;
      constexpr int NIT = (BM * 16) / (TPB * 8);
#pragma unroll
      for (int it = 0; it < NIT; ++it) {
        int lin = it * TPB + tid;
        int c8 = lin & (C8N - 1);
        int colL = lin / C8N;
        int col = (ph << 4) + colL;
        int cell0 = c8 << 3;
        const u32* lp = &L[colL * STC + cell0];
        uint4 d;
        d.x = (lp[0] & 0xffffu) | (lp[1] << 16);
        d.y = (lp[2] & 0xffffu) | (lp[3] << 16);
        d.z = (lp[4] & 0xffffu) | (lp[5] << 16);
        d.w = (lp[6] & 0xffffu) | (lp[7] << 16);
        int gc = m0 + cell0;
        int Xo = gc & (Wi - 1), Yo = (gc >> lwi) & (Wi - 1), bo = gc >> (lwi + lwi);
        *reinterpret_cast<uint4*>(
            &op16[((size_t)(bo * Co + n0 + col) * Hi + Yo) * Wi + Xo]) = d;
      }
    } else {
      u32* op = outq + (size_t)par * QO;
#pragma unroll
      for (int it = 0; it < RM; ++it) {
        int lin = it * TPB + tid;
        int c4 = lin & (C4N - 1);
        int colL = lin / C4N;
        int col = (ph << 4) + colL;
        int cell0 = c4 << 2;
        uint4 d = *reinterpret_cast<const uint4*>(&L[colL * STC + cell0]);
        int gc = m0 + cell0;
        int Xo = gc & (Wi - 1), Yo = (gc >> lwi) & (Wi - 1), bo = gc >> (lwi + lwi);
        *reinterpret_cast<uint4*>(
            &op[((size_t)(bo * Co + n0 + col) * Hi + Yo) * Wi + Xo]) = d;
      }
    }
  }
}

// ---------------- dedicated t3 (u16 bf16 quadrant input) ---------------------
__global__ __launch_bounds__(TPB) void convt3_kernel(
    const u16* __restrict__ inq, const float* __restrict__ w,
    float* __restrict__ part)
{
  __shared__ float wl[3072];
  __shared__ float il[8][33 * 32];
  const int b = blockIdx.x;
  const int z = blockIdx.y;
  const int tid = threadIdx.x;
  for (int i = tid; i < 3072; i += TPB) wl[i] = w[i];
  const int Y = tid >> 3;
  const int X0 = (tid & 7) << 2;
  float acc[3][2][8];
#pragma unroll
  for (int o = 0; o < 3; ++o)
#pragma unroll
    for (int p = 0; p < 2; ++p)
#pragma unroll
      for (int q = 0; q < 8; ++q) acc[o][p][q] = 0.f;

  const int cbeg = z << 5, cend = cbeg + 32;
  for (int c0 = cbeg; c0 < cend; c0 += 8) {
    __syncthreads();
    for (int i = tid; i < 8192; i += TPB) {
      int cc = i >> 10, yy = (i >> 5) & 31, xx = i & 31;
      int q = ((yy & 1) << 1) | (xx & 1);
      il[cc][yy * 33 + xx] = bf2f(inq[(size_t)q * 4194304 +
          (((size_t)b * 64 + c0 + cc) * 16 + (yy >> 1)) * 16 + (xx >> 1)]);
    }
    __syncthreads();
    for (int cc = 0; cc < 8; ++cc) {
      float iv[3][6];
#pragma unroll
      for (int j = 0; j < 3; ++j) {
        int gy = Y - 1 + j;
        int gyc = min(max(gy, 0), 31);
        float my = (gy >= 0 && gy < 32) ? 1.f : 0.f;
#pragma unroll
        for (int k = 0; k < 6; ++k) {
          int gx = X0 - 1 + k;
          int gxc = min(max(gx, 0), 31);
          float mx = (gx >= 0 && gx < 32) ? 1.f : 0.f;
          iv[j][k] = il[cc][gyc * 33 + gxc] * (my * mx);
        }
      }
      const float* wq = &wl[(c0 + cc) * 48];
#pragma unroll
      for (int o = 0; o < 3; ++o) {
        const float* wo = wq + o * 16;
#pragma unroll
        for (int c = 0; c < 4; ++c) {
          acc[o][0][2*c]   = fmaf(iv[1][c+1], wo[5],  acc[o][0][2*c]);
          acc[o][0][2*c]   = fmaf(iv[1][c],   wo[7],  acc[o][0][2*c]);
          acc[o][0][2*c]   = fmaf(iv[0][c+1], wo[13], acc[o][0][2*c]);
          acc[o][0][2*c]   = fmaf(iv[0][c],   wo[15], acc[o][0][2*c]);
          acc[o][0][2*c+1] = fmaf(iv[1][c+2], wo[4],  acc[o][0][2*c+1]);
          acc[o][0][2*c+1] = fmaf(iv[1][c+1], wo[6],  acc[o][0][2*c+1]);
          acc[o][0][2*c+1] = fmaf(iv[0][c+2], wo[12], acc[o][0][2*c+1]);
          acc[o][0][2*c+1] = fmaf(iv[0][c+1], wo[14], acc[o][0][2*c+1]);
          acc[o][1][2*c]   = fmaf(iv[2][c+1], wo[1],  acc[o][1][2*c]);
          acc[o][1][2*c]   = fmaf(iv[2][c],   wo[3],  acc[o][1][2*c]);
          acc[o][1][2*c]   = fmaf(iv[1][c+1], wo[9],  acc[o][1][2*c]);
          acc[o][1][2*c]   = fmaf(iv[1][c],   wo[11], acc[o][1][2*c]);
          acc[o][1][2*c+1] = fmaf(iv[2][c+2], wo[0],  acc[o][1][2*c+1]);
          acc[o][1][2*c+1] = fmaf(iv[2][c+1], wo[2],  acc[o][1][2*c+1]);
          acc[o][1][2*c+1] = fmaf(iv[1][c+2], wo[8],  acc[o][1][2*c+1]);
          acc[o][1][2*c+1] = fmaf(iv[1][c+1], wo[10], acc[o][1][2*c+1]);
        }
      }
    }
  }
  float* pz = part + (size_t)z * 3145728;
#pragma unroll
  for (int o = 0; o < 3; ++o) {
#pragma unroll
    for (int p = 0; p < 2; ++p) {
      float* op = pz + (((size_t)b * 3 + o) * 64 + 2 * Y + p) * 64 + 2 * X0;
      *reinterpret_cast<float4*>(op) =
          make_float4(acc[o][p][0], acc[o][p][1], acc[o][p][2], acc[o][p][3]);
      *reinterpret_cast<float4*>(op + 4) =
          make_float4(acc[o][p][4], acc[o][p][5], acc[o][p][6], acc[o][p][7]);
    }
  }
}

__global__ __launch_bounds__(TPB) void c3_combine(
    const float* __restrict__ part, const float* __restrict__ bias,
    float* __restrict__ out)
{
  int i4 = (blockIdx.x * TPB + threadIdx.x) << 2;
  const float4 p0 = *reinterpret_cast<const float4*>(&part[i4]);
  const float4 p1 = *reinterpret_cast<const float4*>(&part[i4 + 3145728]);
  int o = (i4 >> 12) % 3;
  float bv = bias[o];
  float4 s = make_float4(p0.x + p1.x + bv, p0.y + p1.y + bv,
                         p0.z + p1.z + bv, p0.w + p1.w + bv);
  *reinterpret_cast<float4*>(&out[i4]) = s;
}

// ---------------- VQ: 8 rows/block + fused z_s copy --------------------------
__global__ __launch_bounds__(TPB) void vq8_kernel(
    const float* __restrict__ z, const float* __restrict__ cb,
    float* __restrict__ e, float* __restrict__ rowloss)
{
  __shared__ float cbL[64][65];
  __shared__ float zr[8][64];
  const int tid = threadIdx.x;
  const int lane = tid & 63, wid = tid >> 6;
  const int r0 = blockIdx.x << 3;

  for (int i = tid; i < 512; i += TPB) {
    int rr = i >> 6, k = i & 63;
    int row = r0 + rr;
    int b = row >> 4, s = row & 15;
    zr[rr][k] = z[(size_t)b * 1536 + s * 64 + k];
  }
  {
    int b = r0 >> 4;
    int half = (r0 >> 3) & 1;
    size_t o = (size_t)b * 1536 + 1024 + half * 256 + tid;
    e[o] = z[o];
  }

  float best[2] = {3.4e38f, 3.4e38f};
  int bi[2] = {0, 0};

  for (int c0 = 0; c0 < 512; c0 += 64) {
    __syncthreads();
#pragma unroll
    for (int i = 0; i < 4; ++i) {
      int j = (tid >> 4) + (i << 4);
      int kq = tid & 15;
      const float4 v = *reinterpret_cast<const float4*>(
          &cb[(size_t)(c0 + j) * 64 + (kq << 2)]);
      cbL[(kq << 2) + 0][j] = v.x;
      cbL[(kq << 2) + 1][j] = v.y;
      cbL[(kq << 2) + 2][j] = v.z;
      cbL[(kq << 2) + 3][j] = v.w;
    }
    __syncthreads();
#pragma unroll
    for (int rep = 0; rep < 2; ++rep) {
      const float* zp = zr[wid + (rep << 2)];
      float d = 0.f;
#pragma unroll
      for (int k = 0; k < 64; ++k) {
        float t = zp[k] - cbL[k][lane];
        d = fmaf(t, t, d);
      }
      if (d < best[rep]) { best[rep] = d; bi[rep] = c0 + lane; }
    }
  }
#pragma unroll
  for (int rep = 0; rep < 2; ++rep) {
#pragma unroll
    for (int off = 32; off > 0; off >>= 1) {
      float ob = __shfl_xor(best[rep], off);
      int   oi = __shfl_xor(bi[rep], off);
      if (ob < best[rep] || (ob == best[rep] && oi < bi[rep])) {
        best[rep] = ob; bi[rep] = oi;
      }
    }
    int row = r0 + wid + (rep << 2);
    int b = row >> 4, s = row & 15;
    e[(size_t)b * 1536 + s * 64 + lane] = cb[(size_t)bi[rep] * 64 + lane];
    if (lane == 0) rowloss[row] = best[rep];
  }
}

__global__ __launch_bounds__(TPB) void loss_reduce_kernel(
    const float* __restrict__ rl, float* __restrict__ out)
{
  __shared__ float sm[TPB];
  float s = 0.f;
  for (int i = threadIdx.x; i < 4096; i += TPB) s += rl[i];
  sm[threadIdx.x] = s;
  __syncthreads();
  for (int sft = 128; sft > 0; sft >>= 1) {
    if (threadIdx.x < sft) sm[threadIdx.x] += sm[threadIdx.x + sft];
    __syncthreads();
  }
  if (threadIdx.x == 0) out[0] = sm[0] * (1.25f / 262144.f);
}

// ============================================================================
extern "C" void kernel_launch(void* const* d_in, const int* in_sizes, int n_in,
                              void* d_out, int out_size, void* d_ws, size_t ws_size,
                              hipStream_t stream)
{
  const float* x    = (const float*)d_in[0];
  const float* ew0  = (const float*)d_in[1];
  const float* eb0  = (const float*)d_in[2];
  const float* ew1  = (const float*)d_in[3];
  const float* eb1  = (const float*)d_in[4];
  const float* ew2  = (const float*)d_in[5];
  const float* eb2  = (const float*)d_in[6];
  const float* ew3  = (const float*)d_in[7];
  const float* eb3  = (const float*)d_in[8];
  const float* fw0  = (const float*)d_in[9];
  const float* fb0  = (const float*)d_in[10];
  const float* fw1  = (const float*)d_in[11];
  const float* fb1  = (const float*)d_in[12];
  const float* fw2  = (const float*)d_in[13];
  const float* fb2  = (const float*)d_in[14];
  const float* cb   = (const float*)d_in[15];
  const float* gw0  = (const float*)d_in[16];
  const float* gb0  = (const float*)d_in[17];
  const float* gw1  = (const float*)d_in[18];
  const float* gb1  = (const float*)d_in[19];
  const float* gw2  = (const float*)d_in[20];
  const float* gb2  = (const float*)d_in[21];
  const float* tw0  = (const float*)d_in[22];
  const float* tb0  = (const float*)d_in[23];
  const float* tw1  = (const float*)d_in[24];
  const float* tb1  = (const float*)d_in[25];
  const float* tw2  = (const float*)d_in[26];
  const float* tb2  = (const float*)d_in[27];
  const float* tw3  = (const float*)d_in[28];
  const float* tb3  = (const float*)d_in[29];

  float* out = (float*)d_out;
  float* ws  = (float*)d_ws;

  u16*   WE0  = (u16*)(ws + 0);
  u16*   WE1  = (u16*)(ws + 4608);
  u16*   WE2  = (u16*)(ws + 102912);
  u16*   WE3  = (u16*)(ws + 299520);
  float* RL   = ws + 1085952;
  float* H0P  = ws + 1090048;
  float* PC1  = ws + 20029952;
  float* XP   = ws + 20029952;
  float* H1P  = ws + 1090048;
  float* PC23 = ws + 6398464;
  float* H2P  = ws + 14787072;
  float* H3   = ws + 18063872;
  float* P    = ws + 1090048;
  float* F0   = ws + 5284352;
  float* F1   = ws + 5546496;
  float* Z    = ws + 5808640;
  float* E    = ws + 6201856;
  float* G0   = ws + 6595072;
  float* G1   = ws + 6726144;
  u16*   T2S16= (u16*)(ws + 1090048);
  u16*   WT0h = (u16*)(ws + 17867264);
  u16*   WT1h = (u16*)(ws + 18391552);
  u16*   WT2h = (u16*)(ws + 18522624);
  float* PG2  = ws + 18588160;
  u32*   G2P  = (u32*)(ws + 20685312);
  u32*   T0S  = (u32*)(ws + 21733888);
  u32*   T1S  = (u32*)(ws + 23831040);
  float* PT3  = ws + 18588160;

  // ---- preps: encoder weights + input pad ----
  prep_enc_k<<<dim3(2828), TPB, 0, stream>>>(
      ew0, ew1, ew2, ew3, WE0, WE1, WE2, WE3);
  prep_inp_k<<<dim3(21516), TPB, 0, stream>>>(x, XP, H0P);

  // ---- encoder convs (A-direct MFMA NS=3; NSUB=2 for conv1/2/3) ----
  conv_ad<4,0,4><<<dim3(1024, 1, 1), TPB, 0, stream>>>(
      XP, WE0, eb0, H0P, 3, 64, 64, 5, 1, 48, 3072, 13068, 4356, 0);
  conv_ad<4,1,2><<<dim3(256, 2, 2), TPB, 0, stream>>>(
      H0P, WE1, eb1, PC1, 64, 64, 32, 4, 1, 512, 65536, 73984, 1156, 65536);
  combine_cm_k<<<dim3(20736), TPB, 0, stream>>>(PC1, eb1, H1P);
  conv_ad<4,1,2><<<dim3(64, 4, 4), TPB, 0, stream>>>(
      H1P, WE2, eb2, PC23, 64, 128, 16, 3, 1, 256, 131072, 324, 82944, 16384);
  combine_pad_k<<<dim3(12800), TPB, 0, stream>>>(PC23, eb2, H2P);
  conv_ad<4,1,2><<<dim3(16, 8, 8), TPB, 0, stream>>>(
      H2P, WE3, eb3, PC23, 128, 256, 8, 2, 0, 256, 524288, 12800, 100, 4096);
  conv_combine<<<dim3(1024), TPB, 0, stream>>>(PC23, eb3, H3, 4096, 256, 8, 2, 0);

  // ---- encoder FC (MFMA NS=3, split-K + combine) ----
  gemm_mf<3,0><<<dim3(4, 16, 16), TPB, 0, stream>>>(H3, fw0, fb0, (void*)P, 256, 4096, 1024, 256);
  combine_k<<<dim3(256), TPB, 0, stream>>>(P, fb0, F0, 262144, 1024, 16, 1);
  gemm_mf<3,0><<<dim3(4, 16, 8), TPB, 0, stream>>>(F0, fw1, fb1, (void*)P, 256, 1024, 1024, 128);
  combine_k<<<dim3(256), TPB, 0, stream>>>(P, fb1, F1, 262144, 1024, 8, 1);
  gemm_mf<3,0><<<dim3(4, 24, 8), TPB, 0, stream>>>(F1, fw2, fb2, (void*)P, 256, 1024, 1536, 128);
  combine_k<<<dim3(384), TPB, 0, stream>>>(P, fb2, Z, 393216, 1536, 8, 0);

  // ---- decoder convT weight prep (H2P/H3 dead now -> safe) ----
  prep_dec_k<<<dim3(2816), TPB, 0, stream>>>(tw0, tw1, tw2, WT0h, WT1h, WT2h);

  // ---- VQ (zs copy fused) ----
  vq8_kernel<<<dim3(512), TPB, 0, stream>>>(Z, cb, E, RL);
  loss_reduce_kernel<<<dim3(1), TPB, 0, stream>>>(RL, out + (size_t)out_size - 1);

  // ---- decoder FC (g0/g1 NS=2 split-K; g2 single-term NS=1) ----
  gemm_mf<2,0><<<dim3(4, 8, 8), TPB, 0, stream>>>(E,  gw0, gb0, (void*)P, 256, 1536, 512, 192);
  combine_k<<<dim3(128), TPB, 0, stream>>>(P, gb0, G0, 131072, 512, 8, 1);
  gemm_mf<2,0><<<dim3(4, 16, 4), TPB, 0, stream>>>(G0, gw1, gb1, (void*)P, 256, 512, 1024, 128);
  combine_k<<<dim3(256), TPB, 0, stream>>>(P, gb1, G1, 262144, 1024, 4, 1);

  // g2: single-term split-K z2 -> PG2; combine -> bf16 G2P
  gemm_mf<1,0><<<dim3(4, 64, 2), TPB, 0, stream>>>(G1, gw2, gb2, (void*)PG2, 256, 1024, 4096, 512);
  combine_pk_k<<<dim3(1024), TPB, 0, stream>>>(PG2, gb2, G2P);

  // ---- decoder transposed convs (A-direct single-term bf16) ----
  convt_ad<2,1,0><<<dim3(32, 2, 4),  TPB, 0, stream>>>(G2P, WT0h, tb0, T0S, 256, 128, 4,  2, 1);
  convt_ad<2,1,1><<<dim3(128, 1, 4), TPB, 0, stream>>>(T0S, WT1h, tb1, T1S, 128, 64,  8,  3, 1);
  convt_ad<2,2,1><<<dim3(512, 1, 4), TPB, 0, stream>>>(T1S, WT2h, tb2, (u32*)T2S16, 64, 64, 16, 4, 1);
  convt3_kernel<<<dim3(256, 2), TPB, 0, stream>>>(T2S16, tw3, PT3);
  c3_combine<<<dim3(3072), TPB, 0, stream>>>(PT3, tb3, out);
}

// Round 17
// 491.227 us; speedup vs baseline: 1.0588x; 1.0588x over previous
//
#include <hip/hip_runtime.h>
#include <hip/hip_bf16.h>

// ============================================================================
// VQ-VAE forward, round 17: exact revert to R15 (best measured: 492.6 us).
// R16's NSUB=2 N-split regressed (+6%): A-side gather+split3 work is the
// dominant per-wave cost and N-splitting duplicates it (FETCH 38.5->53MB).
// NSUB stays templated but all launches use NSUB=4 (R15 behavior).
// ============================================================================

#define TPB 256
typedef __attribute__((ext_vector_type(8))) short short8v;
typedef __attribute__((ext_vector_type(4))) float f32x4;
typedef unsigned int u32;
typedef unsigned short u16;

__device__ inline u16 f2bf(float x){
  union { __hip_bfloat16 b; u16 u; } cv;
  cv.b = __float2bfloat16(x);
  return cv.u;
}
__device__ inline float bf2f(u16 h){ union{u32 u;float f;}v; v.u=((u32)h)<<16; return v.f;}

template<int NS>
__device__ inline void splitN(float x, u16 t[3]) {
  u16 h0 = f2bf(x); t[0] = h0;
  float r1 = x - bf2f(h0);
  u16 h1 = f2bf(r1); t[1] = h1;
  if (NS == 3) { float r2 = r1 - bf2f(h1); t[2] = f2bf(r2); }
}

template<int NS, int ST>
__device__ inline void stW(u32* L, int row, int oct, const u16 hs[3][8]) {
  constexpr int SWM = (ST == 64) ? 15 : 7;
  const int sw = row & SWM;
#pragma unroll
  for (int s = 0; s < NS; ++s) {
    uint4 d;
    d.x = (u32)hs[s][0] | ((u32)hs[s][1] << 16);
    d.y = (u32)hs[s][2] | ((u32)hs[s][3] << 16);
    d.z = (u32)hs[s][4] | ((u32)hs[s][5] << 16);
    d.w = (u32)hs[s][6] | ((u32)hs[s][7] << 16);
    int ch = (((s << 2) | oct) ^ sw) << 2;
    *reinterpret_cast<uint4*>(&L[row * ST + ch]) = d;
  }
}

template<int NS, int ST>
__device__ inline void stWf(u32* L, int row, int oct, const float v[8]) {
  u16 hs[3][8];
#pragma unroll
  for (int e = 0; e < 8; ++e) {
    u16 t3[3]; splitN<(NS == 3) ? 3 : 2>(v[e], t3);
    hs[0][e] = t3[0]; hs[1][e] = t3[1]; if (NS == 3) hs[2][e] = t3[2];
  }
  stW<NS, ST>(L, row, oct, hs);
}

template<int ST>
__device__ inline void stWp(u32* L, int row, int oct, int s, uint4 d) {
  constexpr int SWM = (ST == 64) ? 15 : 7;
  int ch = (((s << 2) | oct) ^ (row & SWM)) << 2;
  *reinterpret_cast<uint4*>(&L[row * ST + ch]) = d;
}

template<int ST>
__device__ inline short8v rdFrag(const u32* L, int row, int c) {
  constexpr int SWM = (ST == 64) ? 15 : 7;
  int ph = (c ^ (row & SWM)) << 2;
  return *reinterpret_cast<const short8v*>(&L[row * ST + ph]);
}

// ---------------- weight preps (split for lifetime safety) -------------------
__device__ inline u16 wprep1_elem(const float* __restrict__ src, int i,
                                  int Ci, int Co) {
  int K4 = Ci << 2;
  int par = i / (Co * K4); int rem = i - par * (Co * K4);
  int co = rem / K4; int k4 = rem - co * K4;
  int ci = k4 >> 2, ay = (k4 >> 1) & 1, ax = k4 & 1;
  int py = par >> 1, px = par & 1;
  int widx = ((1 - py) << 2) + (1 - px) + (ay << 3) + (ax << 1);
  return f2bf(src[(((size_t)ci * Co + co) << 4) + widx]);
}
__device__ inline void wsplit3_elem(const float* __restrict__ src,
                                    u16* __restrict__ dst, int i, int n) {
  u16 t3[3]; splitN<3>(src[i], t3);
  dst[i] = t3[0]; dst[i + n] = t3[1]; dst[i + 2 * n] = t3[2];
}

__global__ __launch_bounds__(TPB) void prep_enc_k(
    const float* __restrict__ ew0, const float* __restrict__ ew1,
    const float* __restrict__ ew2, const float* __restrict__ ew3,
    u16* __restrict__ WE0, u16* __restrict__ WE1,
    u16* __restrict__ WE2, u16* __restrict__ WE3)
{
  int idx = blockIdx.x * TPB + threadIdx.x;
  if (idx < 3072)     { wsplit3_elem(ew0, WE0, idx, 3072); return; }
  if (idx < 68608)    { wsplit3_elem(ew1, WE1, idx - 3072, 65536); return; }
  if (idx < 199680)   { wsplit3_elem(ew2, WE2, idx - 68608, 131072); return; }
  if (idx < 723968)   { wsplit3_elem(ew3, WE3, idx - 199680, 524288); return; }
}

__global__ __launch_bounds__(TPB) void prep_dec_k(
    const float* __restrict__ tw0, const float* __restrict__ tw1,
    const float* __restrict__ tw2,
    u16* __restrict__ WT0, u16* __restrict__ WT1, u16* __restrict__ WT2)
{
  int idx = blockIdx.x * TPB + threadIdx.x;
  if (idx < 524288)   { WT0[idx] = wprep1_elem(tw0, idx, 256, 128); return; }
  if (idx < 655360)   { WT1[idx - 524288] = wprep1_elem(tw1, idx - 524288, 128, 64); return; }
  if (idx < 720896)   { WT2[idx - 655360] = wprep1_elem(tw2, idx - 655360, 64, 64); return; }
}

// ---------------- fused input pad / border-zero ------------------------------
__global__ __launch_bounds__(TPB) void prep_inp_k(
    const float* __restrict__ x, float* __restrict__ xp,
    float* __restrict__ h0p)
{
  int idx = blockIdx.x * TPB + threadIdx.x;
  if (idx < 3345408) {
    int px = idx % 66; int t = idx / 66; int py = t % 66; int p = t / 66;
    float v = 0.f;
    if (py >= 1 && py <= 64 && px >= 1 && px <= 64)
      v = x[(size_t)p * 4096 + (py - 1) * 64 + (px - 1)];
    xp[idx] = v;
  } else if (idx < 5508096) {
    int i2 = idx - 3345408;
    int p = i2 / 132, k = i2 % 132;
    int py, px;
    if (k < 34)       { py = 0;           px = k; }
    else if (k < 68)  { py = 33;          px = k - 34; }
    else if (k < 100) { py = k - 68 + 1;  px = 0; }
    else              { py = k - 100 + 1; px = 33; }
    h0p[(size_t)p * 1156 + py * 34 + px] = 0.f;
  }
}

// ---------------- A-direct MFMA conv (s2,k4,p1), NS=3 ------------------------
template<int RM, int OUTM, int NSUB>
__global__ __launch_bounds__(TPB, 2) void conv_ad(
    const float* __restrict__ in, const u16* __restrict__ wsp,
    const float* __restrict__ bias, float* __restrict__ outp,
    int Ci, int Co, int Wi, int lwo, int relu, int KSPL, int PS,
    int bS, int ciS, int Mtot)
{
  constexpr int BM = RM * 64;
  constexpr int NB = NSUB * 16;
  constexpr int BACT = NB * 4;
  __shared__ __align__(16) u32 BL[2][NB * 64];
  const int K = Ci << 4;
  const int PW = Wi + 2;
  const int Wo = Wi >> 1;
  const int tid = threadIdx.x;
  const int m0 = blockIdx.x * BM, n0 = blockIdx.y * NB;
  const int lane = tid & 63, wv = tid >> 6, r = lane & 15, g = lane >> 4;
  const int kb0 = blockIdx.z * KSPL;
  const int kbN = min(kb0 + KSPL, K);
  const int khsel = g & 1;
  const int cig = g >> 1;
  f32x4 acc[RM][NSUB] = {};

  int base[RM];
#pragma unroll
  for (int mm = 0; mm < RM; ++mm) {
    int cell = m0 + (wv * RM + mm) * 16 + r;
    int x = cell & (Wo - 1), y = (cell >> lwo) & (Wo - 1), b = cell >> (lwo + lwo);
    base[mm] = b * bS + (2 * y + 2 * khsel) * PW + 2 * x;
  }

  auto gA = [&](int kb, float v[RM][8]) {
    if ((kb + (g << 3)) < K) {
      int cioff = ((kb >> 4) + cig) * ciS;
#pragma unroll
      for (int mm = 0; mm < RM; ++mm) {
        const float* p = in + base[mm] + cioff;
#pragma unroll
        for (int e = 0; e < 8; ++e)
          v[mm][e] = p[(e >> 2) * PW + (e & 3)];
      }
    } else {
#pragma unroll
      for (int mm = 0; mm < RM; ++mm)
#pragma unroll
        for (int e = 0; e < 8; ++e) v[mm][e] = 0.f;
    }
  };
  auto gB = [&](int kb, uint4* d) {
    if (tid < BACT) {
      int n = tid & (NB - 1), oc2 = tid / NB;
      int k8 = kb + (oc2 << 3);
      if (k8 < K) {
        const u16* wp = wsp + (size_t)(n0 + n) * K + k8;
        d[0] = *reinterpret_cast<const uint4*>(wp);
        d[1] = *reinterpret_cast<const uint4*>(wp + PS);
        d[2] = *reinterpret_cast<const uint4*>(wp + 2 * PS);
        return;
      }
    }
    d[0] = d[1] = d[2] = make_uint4(0u, 0u, 0u, 0u);
  };
  auto mkfrags = [&](const float v[8], short8v f[3]) {
    u16 hs[3][8];
#pragma unroll
    for (int e = 0; e < 8; ++e) {
      u16 t3[3]; splitN<3>(v[e], t3);
      hs[0][e] = t3[0]; hs[1][e] = t3[1]; hs[2][e] = t3[2];
    }
#pragma unroll
    for (int s = 0; s < 3; ++s) {
      union { u16 u[8]; short8v sv; } cv;
#pragma unroll
      for (int e = 0; e < 8; ++e) cv.u[e] = hs[s][e];
      f[s] = cv.sv;
    }
  };

  float vA[RM][8], vA2[RM][8];
  uint4 vB[3], vB2[3];
  gA(kb0, vA); gB(kb0, vB);
  for (int kb = kb0; kb < kbN; kb += 32) {
    u32* BLc = BL[((kb - kb0) >> 5) & 1];
    if (tid < BACT) {
      int n = tid & (NB - 1), oc2 = tid / NB;
      stWp<64>(BLc, n, oc2, 0, vB[0]);
      stWp<64>(BLc, n, oc2, 1, vB[1]);
      stWp<64>(BLc, n, oc2, 2, vB[2]);
    }
    const bool more = (kb + 32) < kbN;
    if (more) { gB(kb + 32, vB2); gA(kb + 32, vA2); }
    short8v a_[RM][3];
#pragma unroll
    for (int mm = 0; mm < RM; ++mm) mkfrags(vA[mm], a_[mm]);
    __syncthreads();
#pragma unroll
    for (int ns = 0; ns < NSUB; ++ns) {
      short8v b_[3];
#pragma unroll
      for (int s = 0; s < 3; ++s) b_[s] = rdFrag<64>(BLc, (ns << 4) + r, (s << 2) | g);
#pragma unroll
      for (int mm = 0; mm < RM; ++mm) {
        acc[mm][ns] = __builtin_amdgcn_mfma_f32_16x16x32_bf16(a_[mm][0], b_[0], acc[mm][ns], 0, 0, 0);
        acc[mm][ns] = __builtin_amdgcn_mfma_f32_16x16x32_bf16(a_[mm][0], b_[1], acc[mm][ns], 0, 0, 0);
        acc[mm][ns] = __builtin_amdgcn_mfma_f32_16x16x32_bf16(a_[mm][1], b_[0], acc[mm][ns], 0, 0, 0);
        acc[mm][ns] = __builtin_amdgcn_mfma_f32_16x16x32_bf16(a_[mm][1], b_[1], acc[mm][ns], 0, 0, 0);
        acc[mm][ns] = __builtin_amdgcn_mfma_f32_16x16x32_bf16(a_[mm][0], b_[2], acc[mm][ns], 0, 0, 0);
        acc[mm][ns] = __builtin_amdgcn_mfma_f32_16x16x32_bf16(a_[mm][2], b_[0], acc[mm][ns], 0, 0, 0);
      }
    }
    if (more) {
#pragma unroll
      for (int mm = 0; mm < RM; ++mm)
#pragma unroll
        for (int e = 0; e < 8; ++e) vA[mm][e] = vA2[mm][e];
#pragma unroll
      for (int s = 0; s < 3; ++s) vB[s] = vB2[s];
    }
  }
#pragma unroll
  for (int mm = 0; mm < RM; ++mm)
#pragma unroll
    for (int ns = 0; ns < NSUB; ++ns) {
      int c0 = m0 + (wv * RM + mm) * 16 + (g << 2);
      int co = n0 + (ns << 4) + r;
      if (OUTM == 0) {
        float bv = bias[co];
        const int OPW = Wo + 2;
        const int OPHW = OPW * OPW;
#pragma unroll
        for (int q = 0; q < 4; ++q) {
          int cell = c0 + q;
          int x = cell & (Wo - 1), y = (cell >> lwo) & (Wo - 1), b = cell >> (lwo + lwo);
          float v = acc[mm][ns][q] + bv;
          if (relu) v = fmaxf(v, 0.f);
          outp[((size_t)(b * Co + co)) * OPHW + (y + 1) * OPW + (x + 1)] = v;
        }
      } else {
        float4 o;
        o.x = acc[mm][ns][0]; o.y = acc[mm][ns][1];
        o.z = acc[mm][ns][2]; o.w = acc[mm][ns][3];
        *reinterpret_cast<float4*>(
            &outp[((size_t)(blockIdx.z * Co + co)) * Mtot + c0]) = o;
      }
    }
}

// ---------------- conv combines ----------------------------------------------
__global__ __launch_bounds__(TPB) void combine_cm_k(
    const float* __restrict__ P, const float* __restrict__ bias,
    float* __restrict__ out)
{
  int idx = blockIdx.x * TPB + threadIdx.x;
  if (idx >= 5308416) return;
  int px = idx % 18; int t = idx / 18; int py = t % 18; t /= 18;
  int b = t % 256; int co = t / 256;
  float v = 0.f;
  if (py >= 1 && py <= 16 && px >= 1 && px <= 16) {
    int cell = b * 256 + (py - 1) * 16 + (px - 1);
    v = P[(size_t)co * 65536 + cell] + P[(size_t)(64 + co) * 65536 + cell] + bias[co];
    v = fmaxf(v, 0.f);
  }
  out[idx] = v;
}

__global__ __launch_bounds__(TPB) void combine_pad_k(
    const float* __restrict__ P, const float* __restrict__ bias,
    float* __restrict__ out)
{
  int idx = blockIdx.x * TPB + threadIdx.x;
  if (idx >= 3276800) return;
  int px = idx % 10; int t = idx / 10; int py = t % 10; t /= 10;
  int co = t % 128; int b = t / 128;
  float v = 0.f;
  if (py >= 1 && py <= 8 && px >= 1 && px <= 8) {
    int cell = b * 64 + (py - 1) * 8 + (px - 1);
    float s = 0.f;
#pragma unroll
    for (int z = 0; z < 4; ++z)
      s += P[((size_t)(z * 128 + co)) * 16384 + cell];
    v = fmaxf(s + bias[co], 0.f);
  }
  out[idx] = v;
}

__global__ __launch_bounds__(TPB) void conv_combine(
    const float* __restrict__ P, const float* __restrict__ bias,
    float* __restrict__ out, int Mtot, int N, int SK, int lwo, int relu)
{
  int idx = blockIdx.x * TPB + threadIdx.x;
  int mq = Mtot >> 2;
  int co = idx / mq;
  int cell0 = (idx - co * mq) << 2;
  if (co >= N) return;
  float4 s = make_float4(0.f, 0.f, 0.f, 0.f);
  for (int z = 0; z < SK; ++z) {
    const float4 pv = *reinterpret_cast<const float4*>(
        &P[((size_t)z * N + co) * Mtot + cell0]);
    s.x += pv.x; s.y += pv.y; s.z += pv.z; s.w += pv.w;
  }
  float bv = bias[co];
  s.x += bv; s.y += bv; s.z += bv; s.w += bv;
  if (relu) { s.x = fmaxf(s.x, 0.f); s.y = fmaxf(s.y, 0.f);
              s.z = fmaxf(s.z, 0.f); s.w = fmaxf(s.w, 0.f); }
  int Wo = 1 << lwo;
  int x = cell0 & (Wo - 1), y = (cell0 >> lwo) & (Wo - 1), b = cell0 >> (lwo + lwo);
  *reinterpret_cast<float4*>(&out[(((size_t)b * N + co) * Wo + y) * Wo + x]) = s;
}

// ---------------- MFMA GEMM (BM=64, BN=64, 4 waves, split-K, prefetched) ----
template<int NS, int OUTM>
__global__ __launch_bounds__(TPB) void gemm_mf(
    const float* __restrict__ A, const float* __restrict__ W,
    const float* __restrict__ bias, void* __restrict__ outp,
    int M, int K, int N, int KSPL)
{
  constexpr int ST = (NS == 3) ? 64 : 32;
  __shared__ __align__(16) u32 L[(64 + 64) * ST];
  u32* AL = L; u32* BL = L + 64 * ST;
  const int tid = threadIdx.x;
  const int m0 = blockIdx.x << 6, n0 = blockIdx.y << 6;
  const int lane = tid & 63, wv = tid >> 6, r = lane & 15, g = lane >> 4;
  const int kb0 = blockIdx.z * KSPL;
  const int kbN = kb0 + KSPL;
  const int cl = tid & 63, oct = tid >> 6;
  f32x4 acc[4] = {};

  float vA[8], vB[8], vA2[8], vB2[8];
  auto gA = [&](int kt, float* v) {
    const float* ap = &A[(size_t)(m0 + cl) * K + kt + (oct << 3)];
    *reinterpret_cast<float4*>(&v[0]) = *reinterpret_cast<const float4*>(ap);
    *reinterpret_cast<float4*>(&v[4]) = *reinterpret_cast<const float4*>(ap + 4);
  };
  auto gB = [&](int kt, float* v) {
#pragma unroll
    for (int e = 0; e < 8; ++e)
      v[e] = W[(size_t)(kt + (oct << 3) + e) * N + n0 + cl];
  };

  gA(kb0, vA); gB(kb0, vB);
  for (int kt = kb0; kt < kbN; kt += 32) {
    const bool more = (kt + 32) < kbN;
    if (more) { gA(kt + 32, vA2); gB(kt + 32, vB2); }
    stWf<NS, ST>(AL, cl, oct, vA);
    stWf<NS, ST>(BL, cl, oct, vB);
    __syncthreads();
    short8v a_[3];
#pragma unroll
    for (int s = 0; s < NS; ++s) a_[s] = rdFrag<ST>(AL, (wv << 4) + r, (s << 2) | g);
#pragma unroll
    for (int ns = 0; ns < 4; ++ns) {
      short8v b_[3];
#pragma unroll
      for (int s = 0; s < NS; ++s) b_[s] = rdFrag<ST>(BL, (ns << 4) + r, (s << 2) | g);
      acc[ns] = __builtin_amdgcn_mfma_f32_16x16x32_bf16(a_[0], b_[0], acc[ns], 0, 0, 0);
      if (NS >= 2) {
        acc[ns] = __builtin_amdgcn_mfma_f32_16x16x32_bf16(a_[0], b_[1], acc[ns], 0, 0, 0);
        acc[ns] = __builtin_amdgcn_mfma_f32_16x16x32_bf16(a_[1], b_[0], acc[ns], 0, 0, 0);
      }
      if (NS == 3) {
        acc[ns] = __builtin_amdgcn_mfma_f32_16x16x32_bf16(a_[1], b_[1], acc[ns], 0, 0, 0);
        acc[ns] = __builtin_amdgcn_mfma_f32_16x16x32_bf16(a_[0], b_[2], acc[ns], 0, 0, 0);
        acc[ns] = __builtin_amdgcn_mfma_f32_16x16x32_bf16(a_[2], b_[0], acc[ns], 0, 0, 0);
      }
    }
    __syncthreads();
    if (more) {
#pragma unroll
      for (int e = 0; e < 8; ++e) { vA[e] = vA2[e]; vB[e] = vB2[e]; }
    }
  }
#pragma unroll
  for (int ns = 0; ns < 4; ++ns)
#pragma unroll
    for (int q = 0; q < 4; ++q) {
      int m = m0 + (wv << 4) + (g << 2) + q;
      int n = n0 + (ns << 4) + r;
      float v = acc[ns][q];
      if (OUTM == 0) ((float*)outp)[((size_t)blockIdx.z * M + m) * N + n] = v;
      else           ((u32*)outp)[(size_t)m * N + n] = (u32)f2bf(v + bias[n]);
    }
}

// ---------------- fc split-K combine ----------------------------------------
__global__ __launch_bounds__(TPB) void combine_k(
    const float* __restrict__ P, const float* __restrict__ bias,
    float* __restrict__ out, int MN, int N, int SK, int relu)
{
  int i4 = (blockIdx.x * TPB + threadIdx.x) << 2;
  if (i4 >= MN) return;
  float4 s = make_float4(0.f, 0.f, 0.f, 0.f);
  for (int z = 0; z < SK; ++z) {
    const float4 pv = *reinterpret_cast<const float4*>(&P[(size_t)z * MN + i4]);
    s.x += pv.x; s.y += pv.y; s.z += pv.z; s.w += pv.w;
  }
  int n = i4 % N;
  s.x += bias[n]; s.y += bias[n + 1]; s.z += bias[n + 2]; s.w += bias[n + 3];
  if (relu) { s.x = fmaxf(s.x, 0.f); s.y = fmaxf(s.y, 0.f);
              s.z = fmaxf(s.z, 0.f); s.w = fmaxf(s.w, 0.f); }
  *reinterpret_cast<float4*>(&out[i4]) = s;
}

// ---------------- g2 combine: sum 2 partials -> single bf16 in u32 ----------
__global__ __launch_bounds__(TPB) void combine_pk_k(
    const float* __restrict__ P, const float* __restrict__ bias,
    u32* __restrict__ out)
{
  int i4 = (blockIdx.x * TPB + threadIdx.x) << 2;
  if (i4 >= 1048576) return;
  const float4 p0 = *reinterpret_cast<const float4*>(&P[i4]);
  const float4 p1 = *reinterpret_cast<const float4*>(&P[1048576 + i4]);
  int n = i4 % 4096;
  uint4 o;
  o.x = (u32)f2bf(p0.x + p1.x + bias[n]);
  o.y = (u32)f2bf(p0.y + p1.y + bias[n + 1]);
  o.z = (u32)f2bf(p0.z + p1.z + bias[n + 2]);
  o.w = (u32)f2bf(p0.w + p1.w + bias[n + 3]);
  *reinterpret_cast<uint4*>(&out[i4]) = o;
}

// ---------------- A-direct MFMA convT, single bf16 term ---------------------
template<int RM, int EMIT, int SPLITIN>
__global__ __launch_bounds__(TPB) void convt_ad(
    const u32* __restrict__ in, const u16* __restrict__ wth,
    const float* __restrict__ bias, u32* __restrict__ outq,
    int Ci, int Co, int Hi, int lwi, int relu)
{
  constexpr int BM = RM * 64;
  constexpr int STC = BM + 4;
  constexpr int LB = 2 * 64 * 32;
  constexpr int LSZ = (LB > 16 * STC) ? LB : 16 * STC;
  __shared__ __align__(16) u32 L[LSZ];
  const int Wi = Hi, K4 = Ci << 2;
  const int HW = Hi * Wi, HWq = HW >> 2, Wiq = Wi >> 1;
  const int par = blockIdx.z, py = par >> 1, px = par & 1;
  const int tid = threadIdx.x;
  const int m0 = blockIdx.x * BM, n0 = blockIdx.y << 6;
  const int lane = tid & 63, wv = tid >> 6, r = lane & 15, g = lane >> 4;
  const int stepCi = SPLITIN ? HWq : HW;
  f32x4 acc[RM][4] = {};

  int offT[RM][4]; u32 mskT[RM][4];
#pragma unroll
  for (int mm = 0; mm < RM; ++mm) {
    int cell = m0 + (wv * RM + mm) * 16 + r;
    int X = cell & (Wi - 1), Y = (cell >> lwi) & (Wi - 1), b = cell >> (lwi + lwi);
#pragma unroll
    for (int t = 0; t < 4; ++t) {
      int ay = t >> 1, ax = t & 1;
      int gy = Y + py - ay, gx = X + px - ax;
      bool ok = (gy >= 0 && gy < Hi && gx >= 0 && gx < Wi);
      int gyc = min(max(gy, 0), Hi - 1), gxc = min(max(gx, 0), Wi - 1);
      if (SPLITIN) {
        int q = ((gyc & 1) << 1) | (gxc & 1);
        offT[mm][t] = q * (256 * Ci * HWq) + b * Ci * HWq + (gyc >> 1) * Wiq + (gxc >> 1);
      } else {
        offT[mm][t] = b * Ci * HW + gyc * Wi + gxc;
      }
      mskT[mm][t] = ok ? 0xffffffffu : 0u;
    }
  }

  auto gA = [&](int kb, u32 v[RM][8]) {
    int cib = ((kb >> 2) + (g << 1)) * stepCi;
#pragma unroll
    for (int mm = 0; mm < RM; ++mm)
#pragma unroll
      for (int e = 0; e < 8; ++e) {
        int t = e & 3;
        v[mm][e] = in[offT[mm][t] + cib + ((e >> 2) ? stepCi : 0)] & mskT[mm][t];
      }
  };
  auto gB = [&](int kb, uint4* d) {
    int n = tid & 63, oc2 = tid >> 6;
    *d = *reinterpret_cast<const uint4*>(
        wth + (size_t)(par * Co + n0 + n) * K4 + kb + (oc2 << 3));
  };

  u32 vA[RM][8], vA2[RM][8];
  uint4 vB, vB2;
  gA(0, vA); gB(0, &vB);
  int cur = 0;
  for (int kb = 0; kb < K4; kb += 32) {
    u32* BLc = L + cur * (64 * 32);
    {
      int n = tid & 63, oc2 = tid >> 6;
      stWp<32>(BLc, n, oc2, 0, vB);
    }
    const bool more = (kb + 32) < K4;
    if (more) { gB(kb + 32, &vB2); gA(kb + 32, vA2); }
    short8v a_[RM];
#pragma unroll
    for (int mm = 0; mm < RM; ++mm) {
      const u32* v = vA[mm];
      union { uint4 u; short8v s; } ch;
      ch.u.x = (v[0] & 0xffffu) | (v[1] << 16);
      ch.u.y = (v[2] & 0xffffu) | (v[3] << 16);
      ch.u.z = (v[4] & 0xffffu) | (v[5] << 16);
      ch.u.w = (v[6] & 0xffffu) | (v[7] << 16);
      a_[mm] = ch.s;
    }
    __syncthreads();
#pragma unroll
    for (int ns = 0; ns < 4; ++ns) {
      short8v b0 = rdFrag<32>(BLc, (ns << 4) + r, g);
#pragma unroll
      for (int mm = 0; mm < RM; ++mm)
        acc[mm][ns] = __builtin_amdgcn_mfma_f32_16x16x32_bf16(a_[mm], b0, acc[mm][ns], 0, 0, 0);
    }
    if (more) {
#pragma unroll
      for (int mm = 0; mm < RM; ++mm)
#pragma unroll
        for (int e = 0; e < 8; ++e) vA[mm][e] = vA2[mm][e];
      vB = vB2;
    }
    cur ^= 1;
  }
  const size_t QO = (size_t)256 * Co * HW;
  constexpr int C4N = BM / 4;
#pragma unroll
  for (int ph = 0; ph < 4; ++ph) {
    __syncthreads();
    float bv = bias[n0 + (ph << 4) + r];
#pragma unroll
    for (int mm = 0; mm < RM; ++mm)
#pragma unroll
      for (int q = 0; q < 4; ++q) {
        int cell = (wv * RM + mm) * 16 + (g << 2) + q;
        float v = acc[mm][ph][q] + bv;
        if (relu) v = fmaxf(v, 0.f);
        L[r * STC + cell] = (u32)f2bf(v);
      }
    __syncthreads();
    if (EMIT == 2) {
      u16* op16 = (u16*)outq + (size_t)par * QO;
      constexpr int C8N = BM / 8;
      constexpr int NIT = (BM * 16) / (TPB * 8);
#pragma unroll
      for (int it = 0; it < NIT; ++it) {
        int lin = it * TPB + tid;
        int c8 = lin & (C8N - 1);
        int colL = lin / C8N;
        int col = (ph << 4) + colL;
        int cell0 = c8 << 3;
        const u32* lp = &L[colL * STC + cell0];
        uint4 d;
        d.x = (lp[0] & 0xffffu) | (lp[1] << 16);
        d.y = (lp[2] & 0xffffu) | (lp[3] << 16);
        d.z = (lp[4] & 0xffffu) | (lp[5] << 16);
        d.w = (lp[6] & 0xffffu) | (lp[7] << 16);
        int gc = m0 + cell0;
        int Xo = gc & (Wi - 1), Yo = (gc >> lwi) & (Wi - 1), bo = gc >> (lwi + lwi);
        *reinterpret_cast<uint4*>(
            &op16[((size_t)(bo * Co + n0 + col) * Hi + Yo) * Wi + Xo]) = d;
      }
    } else {
      u32* op = outq + (size_t)par * QO;
#pragma unroll
      for (int it = 0; it < RM; ++it) {
        int lin = it * TPB + tid;
        int c4 = lin & (C4N - 1);
        int colL = lin / C4N;
        int col = (ph << 4) + colL;
        int cell0 = c4 << 2;
        uint4 d = *reinterpret_cast<const uint4*>(&L[colL * STC + cell0]);
        int gc = m0 + cell0;
        int Xo = gc & (Wi - 1), Yo = (gc >> lwi) & (Wi - 1), bo = gc >> (lwi + lwi);
        *reinterpret_cast<uint4*>(
            &op[((size_t)(bo * Co + n0 + col) * Hi + Yo) * Wi + Xo]) = d;
      }
    }
  }
}

// ---------------- dedicated t3 (u16 bf16 quadrant input) ---------------------
__global__ __launch_bounds__(TPB) void convt3_kernel(
    const u16* __restrict__ inq, const float* __restrict__ w,
    float* __restrict__ part)
{
  __shared__ float wl[3072];
  __shared__ float il[8][33 * 32];
  const int b = blockIdx.x;
  const int z = blockIdx.y;
  const int tid = threadIdx.x;
  for (int i = tid; i < 3072; i += TPB) wl[i] = w[i];
  const int Y = tid >> 3;
  const int X0 = (tid & 7) << 2;
  float acc[3][2][8];
#pragma unroll
  for (int o = 0; o < 3; ++o)
#pragma unroll
    for (int p = 0; p < 2; ++p)
#pragma unroll
      for (int q = 0; q < 8; ++q) acc[o][p][q] = 0.f;

  const int cbeg = z << 5, cend = cbeg + 32;
  for (int c0 = cbeg; c0 < cend; c0 += 8) {
    __syncthreads();
    for (int i = tid; i < 8192; i += TPB) {
      int cc = i >> 10, yy = (i >> 5) & 31, xx = i & 31;
      int q = ((yy & 1) << 1) | (xx & 1);
      il[cc][yy * 33 + xx] = bf2f(inq[(size_t)q * 4194304 +
          (((size_t)b * 64 + c0 + cc) * 16 + (yy >> 1)) * 16 + (xx >> 1)]);
    }
    __syncthreads();
    for (int cc = 0; cc < 8; ++cc) {
      float iv[3][6];
#pragma unroll
      for (int j = 0; j < 3; ++j) {
        int gy = Y - 1 + j;
        int gyc = min(max(gy, 0), 31);
        float my = (gy >= 0 && gy < 32) ? 1.f : 0.f;
#pragma unroll
        for (int k = 0; k < 6; ++k) {
          int gx = X0 - 1 + k;
          int gxc = min(max(gx, 0), 31);
          float mx = (gx >= 0 && gx < 32) ? 1.f : 0.f;
          iv[j][k] = il[cc][gyc * 33 + gxc] * (my * mx);
        }
      }
      const float* wq = &wl[(c0 + cc) * 48];
#pragma unroll
      for (int o = 0; o < 3; ++o) {
        const float* wo = wq + o * 16;
#pragma unroll
        for (int c = 0; c < 4; ++c) {
          acc[o][0][2*c]   = fmaf(iv[1][c+1], wo[5],  acc[o][0][2*c]);
          acc[o][0][2*c]   = fmaf(iv[1][c],   wo[7],  acc[o][0][2*c]);
          acc[o][0][2*c]   = fmaf(iv[0][c+1], wo[13], acc[o][0][2*c]);
          acc[o][0][2*c]   = fmaf(iv[0][c],   wo[15], acc[o][0][2*c]);
          acc[o][0][2*c+1] = fmaf(iv[1][c+2], wo[4],  acc[o][0][2*c+1]);
          acc[o][0][2*c+1] = fmaf(iv[1][c+1], wo[6],  acc[o][0][2*c+1]);
          acc[o][0][2*c+1] = fmaf(iv[0][c+2], wo[12], acc[o][0][2*c+1]);
          acc[o][0][2*c+1] = fmaf(iv[0][c+1], wo[14], acc[o][0][2*c+1]);
          acc[o][1][2*c]   = fmaf(iv[2][c+1], wo[1],  acc[o][1][2*c]);
          acc[o][1][2*c]   = fmaf(iv[2][c],   wo[3],  acc[o][1][2*c]);
          acc[o][1][2*c]   = fmaf(iv[1][c+1], wo[9],  acc[o][1][2*c]);
          acc[o][1][2*c]   = fmaf(iv[1][c],   wo[11], acc[o][1][2*c]);
          acc[o][1][2*c+1] = fmaf(iv[2][c+2], wo[0],  acc[o][1][2*c+1]);
          acc[o][1][2*c+1] = fmaf(iv[2][c+1], wo[2],  acc[o][1][2*c+1]);
          acc[o][1][2*c+1] = fmaf(iv[1][c+2], wo[8],  acc[o][1][2*c+1]);
          acc[o][1][2*c+1] = fmaf(iv[1][c+1], wo[10], acc[o][1][2*c+1]);
        }
      }
    }
  }
  float* pz = part + (size_t)z * 3145728;
#pragma unroll
  for (int o = 0; o < 3; ++o) {
#pragma unroll
    for (int p = 0; p < 2; ++p) {
      float* op = pz + (((size_t)b * 3 + o) * 64 + 2 * Y + p) * 64 + 2 * X0;
      *reinterpret_cast<float4*>(op) =
          make_float4(acc[o][p][0], acc[o][p][1], acc[o][p][2], acc[o][p][3]);
      *reinterpret_cast<float4*>(op + 4) =
          make_float4(acc[o][p][4], acc[o][p][5], acc[o][p][6], acc[o][p][7]);
    }
  }
}

__global__ __launch_bounds__(TPB) void c3_combine(
    const float* __restrict__ part, const float* __restrict__ bias,
    float* __restrict__ out)
{
  int i4 = (blockIdx.x * TPB + threadIdx.x) << 2;
  const float4 p0 = *reinterpret_cast<const float4*>(&part[i4]);
  const float4 p1 = *reinterpret_cast<const float4*>(&part[i4 + 3145728]);
  int o = (i4 >> 12) % 3;
  float bv = bias[o];
  float4 s = make_float4(p0.x + p1.x + bv, p0.y + p1.y + bv,
                         p0.z + p1.z + bv, p0.w + p1.w + bv);
  *reinterpret_cast<float4*>(&out[i4]) = s;
}

// ---------------- VQ: 8 rows/block + fused z_s copy --------------------------
__global__ __launch_bounds__(TPB) void vq8_kernel(
    const float* __restrict__ z, const float* __restrict__ cb,
    float* __restrict__ e, float* __restrict__ rowloss)
{
  __shared__ float cbL[64][65];
  __shared__ float zr[8][64];
  const int tid = threadIdx.x;
  const int lane = tid & 63, wid = tid >> 6;
  const int r0 = blockIdx.x << 3;

  for (int i = tid; i < 512; i += TPB) {
    int rr = i >> 6, k = i & 63;
    int row = r0 + rr;
    int b = row >> 4, s = row & 15;
    zr[rr][k] = z[(size_t)b * 1536 + s * 64 + k];
  }
  {
    int b = r0 >> 4;
    int half = (r0 >> 3) & 1;
    size_t o = (size_t)b * 1536 + 1024 + half * 256 + tid;
    e[o] = z[o];
  }

  float best[2] = {3.4e38f, 3.4e38f};
  int bi[2] = {0, 0};

  for (int c0 = 0; c0 < 512; c0 += 64) {
    __syncthreads();
#pragma unroll
    for (int i = 0; i < 4; ++i) {
      int j = (tid >> 4) + (i << 4);
      int kq = tid & 15;
      const float4 v = *reinterpret_cast<const float4*>(
          &cb[(size_t)(c0 + j) * 64 + (kq << 2)]);
      cbL[(kq << 2) + 0][j] = v.x;
      cbL[(kq << 2) + 1][j] = v.y;
      cbL[(kq << 2) + 2][j] = v.z;
      cbL[(kq << 2) + 3][j] = v.w;
    }
    __syncthreads();
#pragma unroll
    for (int rep = 0; rep < 2; ++rep) {
      const float* zp = zr[wid + (rep << 2)];
      float d = 0.f;
#pragma unroll
      for (int k = 0; k < 64; ++k) {
        float t = zp[k] - cbL[k][lane];
        d = fmaf(t, t, d);
      }
      if (d < best[rep]) { best[rep] = d; bi[rep] = c0 + lane; }
    }
  }
#pragma unroll
  for (int rep = 0; rep < 2; ++rep) {
#pragma unroll
    for (int off = 32; off > 0; off >>= 1) {
      float ob = __shfl_xor(best[rep], off);
      int   oi = __shfl_xor(bi[rep], off);
      if (ob < best[rep] || (ob == best[rep] && oi < bi[rep])) {
        best[rep] = ob; bi[rep] = oi;
      }
    }
    int row = r0 + wid + (rep << 2);
    int b = row >> 4, s = row & 15;
    e[(size_t)b * 1536 + s * 64 + lane] = cb[(size_t)bi[rep] * 64 + lane];
    if (lane == 0) rowloss[row] = best[rep];
  }
}

__global__ __launch_bounds__(TPB) void loss_reduce_kernel(
    const float* __restrict__ rl, float* __restrict__ out)
{
  __shared__ float sm[TPB];
  float s = 0.f;
  for (int i = threadIdx.x; i < 4096; i += TPB) s += rl[i];
  sm[threadIdx.x] = s;
  __syncthreads();
  for (int sft = 128; sft > 0; sft >>= 1) {
    if (threadIdx.x < sft) sm[threadIdx.x] += sm[threadIdx.x + sft];
    __syncthreads();
  }
  if (threadIdx.x == 0) out[0] = sm[0] * (1.25f / 262144.f);
}

// ============================================================================
extern "C" void kernel_launch(void* const* d_in, const int* in_sizes, int n_in,
                              void* d_out, int out_size, void* d_ws, size_t ws_size,
                              hipStream_t stream)
{
  const float* x    = (const float*)d_in[0];
  const float* ew0  = (const float*)d_in[1];
  const float* eb0  = (const float*)d_in[2];
  const float* ew1  = (const float*)d_in[3];
  const float* eb1  = (const float*)d_in[4];
  const float* ew2  = (const float*)d_in[5];
  const float* eb2  = (const float*)d_in[6];
  const float* ew3  = (const float*)d_in[7];
  const float* eb3  = (const float*)d_in[8];
  const float* fw0  = (const float*)d_in[9];
  const float* fb0  = (const float*)d_in[10];
  const float* fw1  = (const float*)d_in[11];
  const float* fb1  = (const float*)d_in[12];
  const float* fw2  = (const float*)d_in[13];
  const float* fb2  = (const float*)d_in[14];
  const float* cb   = (const float*)d_in[15];
  const float* gw0  = (const float*)d_in[16];
  const float* gb0  = (const float*)d_in[17];
  const float* gw1  = (const float*)d_in[18];
  const float* gb1  = (const float*)d_in[19];
  const float* gw2  = (const float*)d_in[20];
  const float* gb2  = (const float*)d_in[21];
  const float* tw0  = (const float*)d_in[22];
  const float* tb0  = (const float*)d_in[23];
  const float* tw1  = (const float*)d_in[24];
  const float* tb1  = (const float*)d_in[25];
  const float* tw2  = (const float*)d_in[26];
  const float* tb2  = (const float*)d_in[27];
  const float* tw3  = (const float*)d_in[28];
  const float* tb3  = (const float*)d_in[29];

  float* out = (float*)d_out;
  float* ws  = (float*)d_ws;

  u16*   WE0  = (u16*)(ws + 0);
  u16*   WE1  = (u16*)(ws + 4608);
  u16*   WE2  = (u16*)(ws + 102912);
  u16*   WE3  = (u16*)(ws + 299520);
  float* RL   = ws + 1085952;
  float* H0P  = ws + 1090048;
  float* PC1  = ws + 20029952;
  float* XP   = ws + 20029952;
  float* H1P  = ws + 1090048;
  float* PC23 = ws + 6398464;
  float* H2P  = ws + 14787072;
  float* H3   = ws + 18063872;
  float* P    = ws + 1090048;
  float* F0   = ws + 5284352;
  float* F1   = ws + 5546496;
  float* Z    = ws + 5808640;
  float* E    = ws + 6201856;
  float* G0   = ws + 6595072;
  float* G1   = ws + 6726144;
  u16*   T2S16= (u16*)(ws + 1090048);
  u16*   WT0h = (u16*)(ws + 17867264);
  u16*   WT1h = (u16*)(ws + 18391552);
  u16*   WT2h = (u16*)(ws + 18522624);
  float* PG2  = ws + 18588160;
  u32*   G2P  = (u32*)(ws + 20685312);
  u32*   T0S  = (u32*)(ws + 21733888);
  u32*   T1S  = (u32*)(ws + 23831040);
  float* PT3  = ws + 18588160;

  // ---- preps: encoder weights + input pad ----
  prep_enc_k<<<dim3(2828), TPB, 0, stream>>>(
      ew0, ew1, ew2, ew3, WE0, WE1, WE2, WE3);
  prep_inp_k<<<dim3(21516), TPB, 0, stream>>>(x, XP, H0P);

  // ---- encoder convs (A-direct MFMA NS=3, R15 grids) ----
  conv_ad<4,0,4><<<dim3(1024, 1, 1), TPB, 0, stream>>>(
      XP, WE0, eb0, H0P, 3, 64, 64, 5, 1, 48, 3072, 13068, 4356, 0);
  conv_ad<4,1,4><<<dim3(256, 1, 2), TPB, 0, stream>>>(
      H0P, WE1, eb1, PC1, 64, 64, 32, 4, 1, 512, 65536, 73984, 1156, 65536);
  combine_cm_k<<<dim3(20736), TPB, 0, stream>>>(PC1, eb1, H1P);
  conv_ad<4,1,4><<<dim3(64, 2, 4), TPB, 0, stream>>>(
      H1P, WE2, eb2, PC23, 64, 128, 16, 3, 1, 256, 131072, 324, 82944, 16384);
  combine_pad_k<<<dim3(12800), TPB, 0, stream>>>(PC23, eb2, H2P);
  conv_ad<4,1,4><<<dim3(16, 4, 8), TPB, 0, stream>>>(
      H2P, WE3, eb3, PC23, 128, 256, 8, 2, 0, 256, 524288, 12800, 100, 4096);
  conv_combine<<<dim3(1024), TPB, 0, stream>>>(PC23, eb3, H3, 4096, 256, 8, 2, 0);

  // ---- encoder FC (MFMA NS=3, split-K + combine) ----
  gemm_mf<3,0><<<dim3(4, 16, 16), TPB, 0, stream>>>(H3, fw0, fb0, (void*)P, 256, 4096, 1024, 256);
  combine_k<<<dim3(256), TPB, 0, stream>>>(P, fb0, F0, 262144, 1024, 16, 1);
  gemm_mf<3,0><<<dim3(4, 16, 8), TPB, 0, stream>>>(F0, fw1, fb1, (void*)P, 256, 1024, 1024, 128);
  combine_k<<<dim3(256), TPB, 0, stream>>>(P, fb1, F1, 262144, 1024, 8, 1);
  gemm_mf<3,0><<<dim3(4, 24, 8), TPB, 0, stream>>>(F1, fw2, fb2, (void*)P, 256, 1024, 1536, 128);
  combine_k<<<dim3(384), TPB, 0, stream>>>(P, fb2, Z, 393216, 1536, 8, 0);

  // ---- decoder convT weight prep (H2P/H3 dead now -> safe) ----
  prep_dec_k<<<dim3(2816), TPB, 0, stream>>>(tw0, tw1, tw2, WT0h, WT1h, WT2h);

  // ---- VQ (zs copy fused) ----
  vq8_kernel<<<dim3(512), TPB, 0, stream>>>(Z, cb, E, RL);
  loss_reduce_kernel<<<dim3(1), TPB, 0, stream>>>(RL, out + (size_t)out_size - 1);

  // ---- decoder FC (g0/g1 NS=2 split-K; g2 single-term NS=1) ----
  gemm_mf<2,0><<<dim3(4, 8, 8), TPB, 0, stream>>>(E,  gw0, gb0, (void*)P, 256, 1536, 512, 192);
  combine_k<<<dim3(128), TPB, 0, stream>>>(P, gb0, G0, 131072, 512, 8, 1);
  gemm_mf<2,0><<<dim3(4, 16, 4), TPB, 0, stream>>>(G0, gw1, gb1, (void*)P, 256, 512, 1024, 128);
  combine_k<<<dim3(256), TPB, 0, stream>>>(P, gb1, G1, 262144, 1024, 4, 1);

  // g2: single-term split-K z2 -> PG2; combine -> bf16 G2P
  gemm_mf<1,0><<<dim3(4, 64, 2), TPB, 0, stream>>>(G1, gw2, gb2, (void*)PG2, 256, 1024, 4096, 512);
  combine_pk_k<<<dim3(1024), TPB, 0, stream>>>(PG2, gb2, G2P);

  // ---- decoder transposed convs (A-direct single-term bf16) ----
  convt_ad<2,1,0><<<dim3(32, 2, 4),  TPB, 0, stream>>>(G2P, WT0h, tb0, T0S, 256, 128, 4,  2, 1);
  convt_ad<2,1,1><<<dim3(128, 1, 4), TPB, 0, stream>>>(T0S, WT1h, tb1, T1S, 128, 64,  8,  3, 1);
  convt_ad<2,2,1><<<dim3(512, 1, 4), TPB, 0, stream>>>(T1S, WT2h, tb2, (u32*)T2S16, 64, 64, 16, 4, 1);
  convt3_kernel<<<dim3(256, 2), TPB, 0, stream>>>(T2S16, tw3, PT3);
  c3_combine<<<dim3(3072), TPB, 0, stream>>>(PT3, tb3, out);
}